// Round 5
// baseline (86.949 us; speedup 1.0000x reference)
//
#include <hip/hip_runtime.h>
#include <hip/hip_bf16.h>

#define B_ 32
#define N_ 1024
#define F_ 128
#define ALPHA_ 0.2f
#define PSTR 72   // padded LDS row stride in bf16 elems (144 B = 9 x 16B slots)

typedef __attribute__((ext_vector_type(8))) short short8_t;
typedef __attribute__((ext_vector_type(4))) short short4_t;
typedef __attribute__((ext_vector_type(4))) float f32x4;

static __device__ __forceinline__ unsigned short bf16b(float f) {
    return __bfloat16_as_ushort(__float2bfloat16(f));
}

// ---------------------------------------------------------------------------
// Kernel A: h = feat @ W^T ; s = h @ a_src ; t = h @ a_dst   (proven, ~5us)
// ---------------------------------------------------------------------------
__global__ __launch_bounds__(256) void hst_kernel(
    const float* __restrict__ feat, const float* __restrict__ W,
    const float* __restrict__ a, float* __restrict__ h,
    float* __restrict__ s_out, float* __restrict__ t_out)
{
    __shared__ unsigned short Wt[128 * 128];
    __shared__ float fl[64 * 128];
    const int tid = threadIdx.x;
    const long row0 = (long)blockIdx.x * 64;

    for (int i = tid; i < 128 * 128; i += 256) {
        int d = i >> 7, k = i & 127;
        Wt[k * 128 + d] = bf16b(W[i]);
    }
    for (int i = tid; i < 64 * 128; i += 256) {
        int r = i >> 7, k = i & 127;
        fl[r * 128 + ((k + 8 * (r >> 2)) & 127)] = feat[(row0 + r) * 128 + k];
    }
    __syncthreads();

    const int oct = tid & 15;
    const int rg  = tid >> 4;
    const int d0  = oct * 8;
    const int r0  = rg * 4;

    float acc[4][8];
    #pragma unroll
    for (int q = 0; q < 4; ++q)
        #pragma unroll
        for (int c = 0; c < 8; ++c) acc[q][c] = 0.f;

    for (int kc = 0; kc < 128; kc += 4) {
        float wv[4][8];
        #pragma unroll
        for (int kk = 0; kk < 4; ++kk) {
            short8_t wr = *reinterpret_cast<const short8_t*>(&Wt[(kc + kk) * 128 + d0]);
            #pragma unroll
            for (int c = 0; c < 8; ++c) {
                union { unsigned u; float f; } cv;
                cv.u = ((unsigned)(unsigned short)wr[c]) << 16;
                wv[kk][c] = cv.f;
            }
        }
        #pragma unroll
        for (int q = 0; q < 4; ++q) {
            int r = r0 + q;
            int koff = (kc + 8 * (r >> 2)) & 127;
            float4 fv = *reinterpret_cast<const float4*>(&fl[r * 128 + koff]);
            float fq[4] = {fv.x, fv.y, fv.z, fv.w};
            #pragma unroll
            for (int kk = 0; kk < 4; ++kk)
                #pragma unroll
                for (int c = 0; c < 8; ++c)
                    acc[q][c] = fmaf(fq[kk], wv[kk][c], acc[q][c]);
        }
    }

    float asrc[8], adst[8];
    #pragma unroll
    for (int c = 0; c < 8; ++c) { asrc[c] = a[d0 + c]; adst[c] = a[128 + d0 + c]; }

    #pragma unroll
    for (int q = 0; q < 4; ++q) {
        long row = row0 + r0 + q;
        float4 h0 = make_float4(acc[q][0], acc[q][1], acc[q][2], acc[q][3]);
        float4 h1 = make_float4(acc[q][4], acc[q][5], acc[q][6], acc[q][7]);
        *reinterpret_cast<float4*>(&h[row * 128 + d0])     = h0;
        *reinterpret_cast<float4*>(&h[row * 128 + d0 + 4]) = h1;
        float sv = 0.f, tv = 0.f;
        #pragma unroll
        for (int c = 0; c < 8; ++c) {
            sv = fmaf(acc[q][c], asrc[c], sv);
            tv = fmaf(acc[q][c], adst[c], tv);
        }
        #pragma unroll
        for (int off = 1; off < 16; off <<= 1) {
            sv += __shfl_xor(sv, off);
            tv += __shfl_xor(tv, off);
        }
        if (oct == 0) { s_out[row] = sv; t_out[row] = tv; }
    }
}

// ---------------------------------------------------------------------------
// Kernel T: hT_bf16[b][d][j] = bf16(h[b][j][d])
// ---------------------------------------------------------------------------
__global__ __launch_bounds__(256) void tr_kernel(
    const float* __restrict__ h, unsigned short* __restrict__ hT)
{
    __shared__ unsigned short lt[128 * PSTR];
    const int tid = threadIdx.x;
    const int b   = blockIdx.x >> 4;
    const int j0  = (blockIdx.x & 15) * 64;

    const int j  = tid >> 2;
    const int dc = (tid & 3) * 4;
    const float* hr = h + ((size_t)(b * N_ + j0 + j)) * F_;
    #pragma unroll
    for (int q = 0; q < 8; ++q) {
        float4 v = *reinterpret_cast<const float4*>(hr + dc + q * 16);
        #pragma unroll
        for (int e = 0; e < 4; ++e)
            lt[(dc + q * 16 + e) * PSTR + j] = bf16b((&v.x)[e]);
    }
    __syncthreads();

    const int d    = tid >> 1;
    const int half = tid & 1;
    unsigned short* dst = hT + ((size_t)b * F_ + d) * N_ + j0 + half * 32;
    #pragma unroll
    for (int q = 0; q < 4; ++q)
        *reinterpret_cast<short8_t*>(dst + q * 8) =
            *reinterpret_cast<const short8_t*>(&lt[d * PSTR + half * 32 + q * 8]);
}

// ---------------------------------------------------------------------------
// Kernel P: bitpack adjacency. Pure linear stream: 128 MB read -> 4 MB write.
// thread i: bits[i] = byte mask of adj[i*8 .. i*8+7]. Diagnostic for adj BW.
// ---------------------------------------------------------------------------
__global__ __launch_bounds__(256) void bitpack_kernel(
    const float* __restrict__ adj, unsigned char* __restrict__ bits)
{
    const size_t nbytes = (size_t)B_ * N_ * N_ / 8;   // 4,194,304
    size_t i = (size_t)blockIdx.x * 256 + threadIdx.x;
    const size_t stride = (size_t)gridDim.x * 256;
    for (; i < nbytes; i += stride) {
        const float4* p = reinterpret_cast<const float4*>(adj + i * 8);
        float4 v0 = p[0];
        float4 v1 = p[1];
        unsigned m = 0;
        m |= (v0.x == 1.0f) ? 1u   : 0u;
        m |= (v0.y == 1.0f) ? 2u   : 0u;
        m |= (v0.z == 1.0f) ? 4u   : 0u;
        m |= (v0.w == 1.0f) ? 8u   : 0u;
        m |= (v1.x == 1.0f) ? 16u  : 0u;
        m |= (v1.y == 1.0f) ? 32u  : 0u;
        m |= (v1.z == 1.0f) ? 64u  : 0u;
        m |= (v1.w == 1.0f) ? 128u : 0u;
        bits[i] = (unsigned char)m;
    }
}

// ---------------------------------------------------------------------------
// Kernel B v5: dense tiled MFMA attention from BITMASK.
// Block = (b, 64-row i-tile): 512 blocks x 512 threads (8 waves, 2m x 4n),
// 2 blocks/CU. Per j-tile of 64: stage hT, gen P from bits (8 KB L1-hot),
// MFMA 16x16x32 accumulate; normalize in epilogue.
// ---------------------------------------------------------------------------
__global__ __launch_bounds__(512, 4) void attn3_kernel(
    const unsigned char* __restrict__ bits, const unsigned short* __restrict__ hT,
    const float* __restrict__ s_in, const float* __restrict__ t_in,
    float* __restrict__ out)
{
    __shared__ unsigned short ht[2][128 * PSTR];  // [d][j]   36864 B
    __shared__ unsigned short pt[2][64 * PSTR];   // [i][j]   18432 B
    __shared__ float tl[N_];                      //           4096 B
    __shared__ float sl[64];
    __shared__ float rsl[64];

    const int tid = threadIdx.x;
    const int b   = blockIdx.x >> 4;
    const int i0  = (blockIdx.x & 15) * 64;

    tl[tid]       = t_in[b * N_ + tid];
    tl[tid + 512] = t_in[b * N_ + tid + 512];
    if (tid < 64) sl[tid] = s_in[b * N_ + i0 + tid];

    // P-gen ids: 8 threads per i-row, 8 j each
    const int gi = tid >> 3;
    const int gj = (tid & 7) * 8;
    const unsigned char* brow = bits + ((size_t)(b * N_ + i0 + gi)) * (N_ / 8);

    const unsigned short* hTb = hT + (size_t)b * F_ * N_;

    short8_t h_reg[2];
    #pragma unroll
    for (int c = 0; c < 2; ++c) {
        int ch = tid + c * 512;
        h_reg[c] = *reinterpret_cast<const short8_t*>(
            hTb + (size_t)(ch >> 3) * N_ + ((ch & 7) * 8));
    }
    __syncthreads();                       // sl/tl visible
    const float s_i = sl[gi];

    // MFMA ids: 8 waves = 2m x 4n; per wave M=32, N=32
    const int w  = tid >> 6;
    const int m0 = (w >> 2) * 32;
    const int n0 = (w & 3) * 32;
    const int lm = tid & 15;
    const int kg = (tid & 63) >> 4;

    f32x4 acc[2][2];
    #pragma unroll
    for (int nf = 0; nf < 2; ++nf)
        #pragma unroll
        for (int mf = 0; mf < 2; ++mf) acc[nf][mf] = (f32x4){0.f, 0.f, 0.f, 0.f};

    float rs = 0.f;

    for (int k = 0; k < 16; ++k) {
        const int cur = k & 1;
        // ---- STAGE ht (from regs loaded last iter) ----
        #pragma unroll
        for (int c = 0; c < 2; ++c) {
            int ch = tid + c * 512;
            *reinterpret_cast<short8_t*>(&ht[cur][(ch >> 3) * PSTR + (ch & 7) * 8]) = h_reg[c];
        }
        // ---- P-gen from bitmask (L1-hot: 8 KB per block) ----
        {
            unsigned bm = brow[k * 8 + (tid & 7)];
            float4 t40 = *reinterpret_cast<const float4*>(&tl[k * 64 + gj]);
            float4 t41 = *reinterpret_cast<const float4*>(&tl[k * 64 + gj + 4]);
            short4_t pk0, pk1;
            #pragma unroll
            for (int e = 0; e < 4; ++e) {
                float sc = s_i + (&t40.x)[e];
                sc = fmaxf(sc, ALPHA_ * sc);
                float p = __expf(sc) * (float)((bm >> e) & 1u);
                rs += p;
                pk0[e] = (short)bf16b(p);
            }
            #pragma unroll
            for (int e = 0; e < 4; ++e) {
                float sc = s_i + (&t41.x)[e];
                sc = fmaxf(sc, ALPHA_ * sc);
                float p = __expf(sc) * (float)((bm >> (e + 4)) & 1u);
                rs += p;
                pk1[e] = (short)bf16b(p);
            }
            *reinterpret_cast<short4_t*>(&pt[cur][gi * PSTR + gj])     = pk0;
            *reinterpret_cast<short4_t*>(&pt[cur][gi * PSTR + gj + 4]) = pk1;
        }
        // ---- prefetch next ht tile into regs ----
        if (k < 15) {
            #pragma unroll
            for (int c = 0; c < 2; ++c) {
                int ch = tid + c * 512;
                h_reg[c] = *reinterpret_cast<const short8_t*>(
                    hTb + (size_t)(ch >> 3) * N_ + ((k + 1) * 64 + (ch & 7) * 8));
            }
        }
        __syncthreads();                   // stage visible to all waves
        // ---- MFMA ----
        #pragma unroll
        for (int ks = 0; ks < 2; ++ks) {
            short8_t bfr[2];
            #pragma unroll
            for (int nf = 0; nf < 2; ++nf)
                bfr[nf] = *reinterpret_cast<const short8_t*>(
                    &ht[cur][(n0 + nf * 16 + lm) * PSTR + ks * 32 + kg * 8]);
            #pragma unroll
            for (int mf = 0; mf < 2; ++mf) {
                short8_t afr = *reinterpret_cast<const short8_t*>(
                    &pt[cur][(m0 + mf * 16 + lm) * PSTR + ks * 32 + kg * 8]);
                acc[0][mf] = __builtin_amdgcn_mfma_f32_16x16x32_bf16(
                    afr, bfr[0], acc[0][mf], 0, 0, 0);
                acc[1][mf] = __builtin_amdgcn_mfma_f32_16x16x32_bf16(
                    afr, bfr[1], acc[1][mf], 0, 0, 0);
            }
        }
    }

    // rowsum: reduce over the 8 threads sharing gi (consecutive lanes)
    rs += __shfl_xor(rs, 1);
    rs += __shfl_xor(rs, 2);
    rs += __shfl_xor(rs, 4);
    if ((tid & 7) == 0) rsl[gi] = 1.0f / rs;
    __syncthreads();

    // epilogue: out[b, i0+row, col] = acc * inv_rowsum
    const int rbase = m0 + ((tid & 63) >> 4) * 4;
    float* ob = out + ((size_t)(b * N_ + i0)) * F_;
    #pragma unroll
    for (int mf = 0; mf < 2; ++mf) {
        f32x4 inv = *reinterpret_cast<const f32x4*>(&rsl[rbase + mf * 16]);
        #pragma unroll
        for (int r = 0; r < 4; ++r) {
            int row = rbase + mf * 16 + r;
            #pragma unroll
            for (int nf = 0; nf < 2; ++nf)
                ob[(size_t)row * F_ + n0 + nf * 16 + lm] = acc[nf][mf][r] * inv[r];
        }
    }
}

// ---------------------------------------------------------------------------
extern "C" void kernel_launch(void* const* d_in, const int* in_sizes, int n_in,
                              void* d_out, int out_size, void* d_ws, size_t ws_size,
                              hipStream_t stream)
{
    const float* adj  = (const float*)d_in[0];   // (32,1024,1024)
    const float* feat = (const float*)d_in[1];   // (32,1024,128)
    const float* W    = (const float*)d_in[2];   // (128,128)
    const float* a    = (const float*)d_in[3];   // (256,1)
    float* out = (float*)d_out;                  // (32,1024,128) fp32

    float* h = (float*)d_out;                    // scratch: h fp32, dead before attn3 writes
    unsigned short* hT = (unsigned short*)d_ws;                          // 8 MB
    float* s = (float*)((char*)d_ws + (size_t)B_ * F_ * N_ * 2);         // 128 KB
    float* t = s + (size_t)B_ * N_;                                      // 128 KB
    unsigned char* bits = (unsigned char*)(t + (size_t)B_ * N_);         // 4 MB

    hst_kernel<<<(B_ * N_) / 64, 256, 0, stream>>>(feat, W, a, h, s, t);
    tr_kernel<<<B_ * 16, 256, 0, stream>>>(h, hT);
    bitpack_kernel<<<2048, 256, 0, stream>>>(adj, bits);
    attn3_kernel<<<B_ * 16, 512, 0, stream>>>(bits, hT, s, t, out);
}

// Round 6
// 72.153 us; speedup vs baseline: 1.2051x; 1.2051x over previous
//
#include <hip/hip_runtime.h>
#include <hip/hip_bf16.h>

#define B_ 32
#define N_ 1024
#define F_ 128
#define ALPHA_ 0.2f
#define PSTR 72   // padded LDS row stride in bf16 elems (144 B = 9 x 16B slots)

typedef __attribute__((ext_vector_type(8))) short short8_t;
typedef __attribute__((ext_vector_type(4))) short short4_t;
typedef __attribute__((ext_vector_type(4))) float f32x4;

static __device__ __forceinline__ unsigned short bf16b(float f) {
    return __bfloat16_as_ushort(__float2bfloat16(f));
}

#define WAIT_VM2()  asm volatile("s_waitcnt vmcnt(2)" ::: "memory")
#define WAIT_VM0()  asm volatile("s_waitcnt vmcnt(0)" ::: "memory")
#define WAIT_LGKM() asm volatile("s_waitcnt lgkmcnt(0)" ::: "memory")
#define SCHEDB()    __builtin_amdgcn_sched_barrier(0)
#define BAR()       __builtin_amdgcn_s_barrier()

// ---------------------------------------------------------------------------
// Kernel A: h = feat @ W^T ; s = h @ a_src ; t = h @ a_dst   (proven, ~5us)
// ---------------------------------------------------------------------------
__global__ __launch_bounds__(256) void hst_kernel(
    const float* __restrict__ feat, const float* __restrict__ W,
    const float* __restrict__ a, float* __restrict__ h,
    float* __restrict__ s_out, float* __restrict__ t_out)
{
    __shared__ unsigned short Wt[128 * 128];
    __shared__ float fl[64 * 128];
    const int tid = threadIdx.x;
    const long row0 = (long)blockIdx.x * 64;

    for (int i = tid; i < 128 * 128; i += 256) {
        int d = i >> 7, k = i & 127;
        Wt[k * 128 + d] = bf16b(W[i]);
    }
    for (int i = tid; i < 64 * 128; i += 256) {
        int r = i >> 7, k = i & 127;
        fl[r * 128 + ((k + 8 * (r >> 2)) & 127)] = feat[(row0 + r) * 128 + k];
    }
    __syncthreads();

    const int oct = tid & 15;
    const int rg  = tid >> 4;
    const int d0  = oct * 8;
    const int r0  = rg * 4;

    float acc[4][8];
    #pragma unroll
    for (int q = 0; q < 4; ++q)
        #pragma unroll
        for (int c = 0; c < 8; ++c) acc[q][c] = 0.f;

    for (int kc = 0; kc < 128; kc += 4) {
        float wv[4][8];
        #pragma unroll
        for (int kk = 0; kk < 4; ++kk) {
            short8_t wr = *reinterpret_cast<const short8_t*>(&Wt[(kc + kk) * 128 + d0]);
            #pragma unroll
            for (int c = 0; c < 8; ++c) {
                union { unsigned u; float f; } cv;
                cv.u = ((unsigned)(unsigned short)wr[c]) << 16;
                wv[kk][c] = cv.f;
            }
        }
        #pragma unroll
        for (int q = 0; q < 4; ++q) {
            int r = r0 + q;
            int koff = (kc + 8 * (r >> 2)) & 127;
            float4 fv = *reinterpret_cast<const float4*>(&fl[r * 128 + koff]);
            float fq[4] = {fv.x, fv.y, fv.z, fv.w};
            #pragma unroll
            for (int kk = 0; kk < 4; ++kk)
                #pragma unroll
                for (int c = 0; c < 8; ++c)
                    acc[q][c] = fmaf(fq[kk], wv[kk][c], acc[q][c]);
        }
    }

    float asrc[8], adst[8];
    #pragma unroll
    for (int c = 0; c < 8; ++c) { asrc[c] = a[d0 + c]; adst[c] = a[128 + d0 + c]; }

    #pragma unroll
    for (int q = 0; q < 4; ++q) {
        long row = row0 + r0 + q;
        float4 h0 = make_float4(acc[q][0], acc[q][1], acc[q][2], acc[q][3]);
        float4 h1 = make_float4(acc[q][4], acc[q][5], acc[q][6], acc[q][7]);
        *reinterpret_cast<float4*>(&h[row * 128 + d0])     = h0;
        *reinterpret_cast<float4*>(&h[row * 128 + d0 + 4]) = h1;
        float sv = 0.f, tv = 0.f;
        #pragma unroll
        for (int c = 0; c < 8; ++c) {
            sv = fmaf(acc[q][c], asrc[c], sv);
            tv = fmaf(acc[q][c], adst[c], tv);
        }
        #pragma unroll
        for (int off = 1; off < 16; off <<= 1) {
            sv += __shfl_xor(sv, off);
            tv += __shfl_xor(tv, off);
        }
        if (oct == 0) { s_out[row] = sv; t_out[row] = tv; }
    }
}

// ---------------------------------------------------------------------------
// Kernel T: hT_bf16[b][d][j] = bf16(h[b][j][d])
// ---------------------------------------------------------------------------
__global__ __launch_bounds__(256) void tr_kernel(
    const float* __restrict__ h, unsigned short* __restrict__ hT)
{
    __shared__ unsigned short lt[128 * PSTR];
    const int tid = threadIdx.x;
    const int b   = blockIdx.x >> 4;
    const int j0  = (blockIdx.x & 15) * 64;

    const int j  = tid >> 2;
    const int dc = (tid & 3) * 4;
    const float* hr = h + ((size_t)(b * N_ + j0 + j)) * F_;
    #pragma unroll
    for (int q = 0; q < 8; ++q) {
        float4 v = *reinterpret_cast<const float4*>(hr + dc + q * 16);
        #pragma unroll
        for (int e = 0; e < 4; ++e)
            lt[(dc + q * 16 + e) * PSTR + j] = bf16b((&v.x)[e]);
    }
    __syncthreads();

    const int d    = tid >> 1;
    const int half = tid & 1;
    unsigned short* dst = hT + ((size_t)b * F_ + d) * N_ + j0 + half * 32;
    #pragma unroll
    for (int q = 0; q < 4; ++q)
        *reinterpret_cast<short8_t*>(dst + q * 8) =
            *reinterpret_cast<const short8_t*>(&lt[d * PSTR + half * 32 + q * 8]);
}

// ---------------------------------------------------------------------------
// Kernel B v6: fused MFMA attention; adj streamed via global_load_lds with
// counted-vmcnt pipeline (never drains mid-loop). Block = (b, 64-row i-tile):
// 512 blocks x 512 threads (8 waves), LDS 63 KB -> 2 blocks/CU.
// Per j-tile k: [issue adj(k+1) DMA] [stage ht] [P-gen from adjb[k&1]]
// [issue h(k+1)] [lgkm+bar] [MFMA] [vmcnt(2)+bar proves adj(k+1)].
// ---------------------------------------------------------------------------
__global__ __launch_bounds__(512, 4) void attn4_kernel(
    const float* __restrict__ adj, const unsigned short* __restrict__ hT,
    const float* __restrict__ s_in, const float* __restrict__ t_in,
    float* __restrict__ out)
{
    __shared__ float adjb[2][64 * 64];            // 32 KB, DMA double-buffer
    __shared__ unsigned short ht[128 * PSTR];     // 18 KB
    __shared__ unsigned short pt[64 * PSTR];      //  9 KB
    __shared__ float tl[N_];                      //  4 KB
    __shared__ float sl[64], rsl[64];

    const int tid  = threadIdx.x;
    const int lane = tid & 63;
    const int w    = tid >> 6;

    // XCD-chunked swizzle: 512 blocks, XCD = blockIdx%8 -> give it a
    // contiguous 64-block chunk (2 whole batches per XCD).
    const int blk = (blockIdx.x & 7) * 64 + (blockIdx.x >> 3);
    const int b   = blk >> 4;
    const int i0  = (blk & 15) * 64;

    tl[tid]       = t_in[b * N_ + tid];
    tl[tid + 512] = t_in[b * N_ + tid + 512];
    if (tid < 64) sl[tid] = s_in[b * N_ + i0 + tid];

    // adj DMA addressing: issue q of wave w covers tile elements
    // (w*2+q)*256 + lane*4  ->  row sr+q*4, col sc (4 floats)
    const int sr = w * 8 + (lane >> 4);
    const int sc = (lane & 15) * 4;
    const float* gsrc = adj + (size_t)(b * N_ + i0) * N_;

#define STAGE_ADJ(K, BUF) do {                                                 \
    __builtin_amdgcn_global_load_lds(                                          \
        (const __attribute__((address_space(1))) void*)                        \
            (gsrc + (size_t)sr * N_ + (K) * 64 + sc),                          \
        (__attribute__((address_space(3))) void*)&adjb[BUF][(w * 2 + 0) * 256],\
        16, 0, 0);                                                             \
    __builtin_amdgcn_global_load_lds(                                          \
        (const __attribute__((address_space(1))) void*)                        \
            (gsrc + (size_t)(sr + 4) * N_ + (K) * 64 + sc),                    \
        (__attribute__((address_space(3))) void*)&adjb[BUF][(w * 2 + 1) * 256],\
        16, 0, 0);                                                             \
} while (0)

    // ht staging (reg <- global, L2-hot)
    const unsigned short* hTb = hT + (size_t)b * F_ * N_;
    short8_t h_reg[2];
#define LOAD_H(K) do {                                                         \
    _Pragma("unroll")                                                          \
    for (int c = 0; c < 2; ++c) {                                              \
        int ch = tid + c * 512;                                                \
        h_reg[c] = *reinterpret_cast<const short8_t*>(                         \
            hTb + (size_t)(ch >> 3) * N_ + ((K) * 64 + (ch & 7) * 8));         \
    }                                                                          \
} while (0)

    // P-gen ids: 8 threads/row, 8 j each
    const int gi = tid >> 3;
    const int gj = (tid & 7) * 8;
    // MFMA ids: 8 waves = 2m x 4n, per-wave 32x32
    const int m0 = (w >> 2) * 32;
    const int n0 = (w & 3) * 32;
    const int lm = tid & 15;
    const int kg = (tid & 63) >> 4;

    f32x4 acc[2][2];
    #pragma unroll
    for (int nf = 0; nf < 2; ++nf)
        #pragma unroll
        for (int mf = 0; mf < 2; ++mf) acc[nf][mf] = (f32x4){0.f, 0.f, 0.f, 0.f};
    float rs = 0.f;

    // ---- prologue: tile 0 in flight, then prove it ----
    STAGE_ADJ(0, 0);
    LOAD_H(0);
    WAIT_VM2();          // adj(0) done (h(0) may remain)
    WAIT_LGKM();         // tl/sl visible
    SCHEDB();
    BAR();
    const float s_i = sl[gi];

    #pragma unroll
    for (int k = 0; k < 16; ++k) {
        const int cur = k & 1;
        // 1. issue next adj tile DMA (stays in flight across both barriers)
        if (k + 1 < 16) STAGE_ADJ(k + 1, cur ^ 1);
        // 2. stage ht from regs (compiler inserts precise vmcnt for h_reg)
        #pragma unroll
        for (int c = 0; c < 2; ++c) {
            int ch = tid + c * 512;
            *reinterpret_cast<short8_t*>(&ht[(ch >> 3) * PSTR + (ch & 7) * 8]) = h_reg[c];
        }
        // 3. P-gen from adjb[cur] (proven complete by previous iteration)
        {
            float4 a0 = *reinterpret_cast<const float4*>(&adjb[cur][gi * 64 + gj]);
            float4 a1 = *reinterpret_cast<const float4*>(&adjb[cur][gi * 64 + gj + 4]);
            float4 t0 = *reinterpret_cast<const float4*>(&tl[k * 64 + gj]);
            float4 t1 = *reinterpret_cast<const float4*>(&tl[k * 64 + gj + 4]);
            short4_t pk0, pk1;
            #pragma unroll
            for (int e = 0; e < 4; ++e) {
                float sc0 = s_i + (&t0.x)[e];
                sc0 = fmaxf(sc0, ALPHA_ * sc0);
                float p = __expf(sc0) * (&a0.x)[e];   // adj is exactly 0.0/1.0
                rs += p;
                pk0[e] = (short)bf16b(p);
            }
            #pragma unroll
            for (int e = 0; e < 4; ++e) {
                float sc1 = s_i + (&t1.x)[e];
                sc1 = fmaxf(sc1, ALPHA_ * sc1);
                float p = __expf(sc1) * (&a1.x)[e];
                rs += p;
                pk1[e] = (short)bf16b(p);
            }
            *reinterpret_cast<short4_t*>(&pt[gi * PSTR + gj])     = pk0;
            *reinterpret_cast<short4_t*>(&pt[gi * PSTR + gj + 4]) = pk1;
        }
        // 4. issue next ht loads (in flight across barrier + MFMA)
        if (k + 1 < 16) LOAD_H(k + 1);
        // 5. ht/pt visible to all waves
        WAIT_LGKM();
        SCHEDB();
        BAR();
        // 6. MFMA
        #pragma unroll
        for (int ks = 0; ks < 2; ++ks) {
            short8_t b0 = *reinterpret_cast<const short8_t*>(
                &ht[(n0 + lm) * PSTR + ks * 32 + kg * 8]);
            short8_t b1 = *reinterpret_cast<const short8_t*>(
                &ht[(n0 + 16 + lm) * PSTR + ks * 32 + kg * 8]);
            short8_t a0f = *reinterpret_cast<const short8_t*>(
                &pt[(m0 + lm) * PSTR + ks * 32 + kg * 8]);
            short8_t a1f = *reinterpret_cast<const short8_t*>(
                &pt[(m0 + 16 + lm) * PSTR + ks * 32 + kg * 8]);
            acc[0][0] = __builtin_amdgcn_mfma_f32_16x16x32_bf16(a0f, b0, acc[0][0], 0, 0, 0);
            acc[1][0] = __builtin_amdgcn_mfma_f32_16x16x32_bf16(a0f, b1, acc[1][0], 0, 0, 0);
            acc[0][1] = __builtin_amdgcn_mfma_f32_16x16x32_bf16(a1f, b0, acc[0][1], 0, 0, 0);
            acc[1][1] = __builtin_amdgcn_mfma_f32_16x16x32_bf16(a1f, b1, acc[1][1], 0, 0, 0);
        }
        // 7. prove adj(k+1) complete across all waves; keep h(k+1) in flight
        if (k + 1 < 16) { WAIT_VM2(); } else { WAIT_VM0(); }
        SCHEDB();
        BAR();
    }

    // rowsum over the 8 threads sharing gi
    rs += __shfl_xor(rs, 1);
    rs += __shfl_xor(rs, 2);
    rs += __shfl_xor(rs, 4);
    if ((tid & 7) == 0) rsl[gi] = 1.0f / rs;
    __syncthreads();

    const int rbase = m0 + ((tid & 63) >> 4) * 4;
    float* ob = out + ((size_t)(b * N_ + i0)) * F_;
    #pragma unroll
    for (int mf = 0; mf < 2; ++mf) {
        f32x4 inv = *reinterpret_cast<const f32x4*>(&rsl[rbase + mf * 16]);
        #pragma unroll
        for (int r = 0; r < 4; ++r) {
            int row = rbase + mf * 16 + r;
            #pragma unroll
            for (int nf = 0; nf < 2; ++nf)
                ob[(size_t)row * F_ + n0 + nf * 16 + lm] = acc[nf][mf][r] * inv[r];
        }
    }
#undef STAGE_ADJ
#undef LOAD_H
}

// ---------------------------------------------------------------------------
extern "C" void kernel_launch(void* const* d_in, const int* in_sizes, int n_in,
                              void* d_out, int out_size, void* d_ws, size_t ws_size,
                              hipStream_t stream)
{
    const float* adj  = (const float*)d_in[0];   // (32,1024,1024)
    const float* feat = (const float*)d_in[1];   // (32,1024,128)
    const float* W    = (const float*)d_in[2];   // (128,128)
    const float* a    = (const float*)d_in[3];   // (256,1)
    float* out = (float*)d_out;                  // (32,1024,128) fp32

    float* h = (float*)d_out;                    // scratch: dead before attn4 writes
    unsigned short* hT = (unsigned short*)d_ws;                          // 8 MB
    float* s = (float*)((char*)d_ws + (size_t)B_ * F_ * N_ * 2);         // 128 KB
    float* t = s + (size_t)B_ * N_;                                      // 128 KB

    hst_kernel<<<(B_ * N_) / 64, 256, 0, stream>>>(feat, W, a, h, s, t);
    tr_kernel<<<B_ * 16, 256, 0, stream>>>(h, hT);
    attn4_kernel<<<B_ * 16, 512, 0, stream>>>(adj, hT, s, t, out);
}